// Round 4
// baseline (105.656 us; speedup 1.0000x reference)
//
#include <hip/hip_runtime.h>
#include <hip/hip_bf16.h>
#include <cstdint>

#define BATCH 16
#define TTOT  4096
#define DIN   512
#define DOUT  512
#define NG    8
#define NJOB  33

typedef float f32x4 __attribute__((ext_vector_type(4)));
typedef short s16x8 __attribute__((ext_vector_type(8)));

__device__ __forceinline__ short f2b(float f) {
    union { __bf16 b; short s; } u; u.b = (__bf16)f; return u.s;
}

// M-tile jobs per batch: 31 full 128-row tiles + two 64-row stubs at 3584/3648.
__device__ __constant__ short JT0[NJOB] = {
    0,128, 256,384,512,640, 768,896,1024,1152,1280,1408, 1536,1664,1792,
    1920,2048,2176,2304,2432, 2560,2688,2816,2944, 3072,3200,3328,3456,
    3584, 3648, 3712,3840,3968};
__device__ __constant__ char JG[NJOB] = {
    0,0, 1,1,1,1, 2,2,2,2,2,2, 3,3,3, 4,4,4,4,4, 5,5,5,5, 6,6,6,6, 6, 7, 7,7,7};
__device__ __constant__ char JNW[NJOB] = {
    8,8, 8,8,8,8, 8,8,8,8,8,8, 8,8,8, 8,8,8,8,8, 8,8,8,8, 8,8,8,8, 4, 4, 8,8,8};

// ---- Kernel 1: W fp32 -> bf16, PRE-SWIZZLED LDS-image chunks in workspace ----
// chunk c = (g*4 + nt)*8 + kt, 16384 B each; chunk[row*128 + bc] holds
// bf16 of W[g][nt*128+row][kt*64 + ((bc ^ ((row&7)<<4))>>1)]
__global__ void wconv_kernel(const float* __restrict__ W, ushort* __restrict__ wbf) {
    int gid = blockIdx.x * 256 + threadIdx.x;
    int c = gid >> 10;
    int q = (gid & 1023) << 4;
    int row = q >> 7;
    int bc  = q & 127;
    int kbyte = bc ^ ((row & 7) << 4);
    int kt = c & 7, nt = (c >> 3) & 3, g = c >> 5;
    const float* wp = W + ((size_t)(g * DOUT + nt * 128 + row)) * DIN
                        + kt * 64 + (kbyte >> 1);
    float4 v0 = *reinterpret_cast<const float4*>(wp);
    float4 v1 = *reinterpret_cast<const float4*>(wp + 4);
    s16x8 o;
    o[0]=f2b(v0.x); o[1]=f2b(v0.y); o[2]=f2b(v0.z); o[3]=f2b(v0.w);
    o[4]=f2b(v1.x); o[5]=f2b(v1.y); o[6]=f2b(v1.z); o[7]=f2b(v1.w);
    *reinterpret_cast<s16x8*>((char*)wbf + (size_t)c * 16384 + q) = o;
}

// ---- Kernel 2: persistent grouped GEMM. 256 blocks x 512 thr (8 waves).
// B (128x512 bf16 = 128KB) fully LDS-resident per (g,nt) run; A streamed via
// per-wave 4-slot register ring (lead 3); NO barriers in the K loop.
__launch_bounds__(512, 2)
__global__ void gemm_kernel(const float* __restrict__ x,
                            const ushort* __restrict__ wbf,
                            const float* __restrict__ bias,
                            float* __restrict__ out) {
    __shared__ __align__(16) char smem[147968];   // 128KB B + 8 x 2112B C-slices
    char* ldsB = smem;
    const int tid  = threadIdx.x;
    const int lane = tid & 63;
    const int wv   = tid >> 6;                    // 0..7 : 16-row stripe owner
    const int colf = lane & 15;
    const int kg   = lane >> 4;
    float* cslice = (float*)(smem + 131072 + wv * 2112);

    // persistent work split: block p -> XCD-contiguous slot l -> rank window
    const int p  = blockIdx.x;
    const int l  = ((p & 7) << 5) + (p >> 3);     // 0..255, contiguous per XCD
    const int r0   = (l < 64) ? l * 9 : 8 * l + 64;
    const int rend = r0 + ((l < 64) ? 9 : 8);

    float4 st0[4], st1[4], st2[4], st3[4];

#define ISSUE(S, P, KT_) do {                                               \
        const float* p_ = (P) + ((KT_) << 6) + (kg << 3);                   \
        st##S[0] = *(const float4*)(p_);                                    \
        st##S[1] = *(const float4*)(p_ + 4);                                \
        st##S[2] = *(const float4*)(p_ + 32);                               \
        st##S[3] = *(const float4*)(p_ + 36);                               \
    } while (0)

#define CONSUME(S, KT_) do {                                                \
        _Pragma("unroll")                                                   \
        for (int ks = 0; ks < 2; ++ks) {                                    \
            float4 f0 = st##S[ks*2], f1 = st##S[ks*2+1];                    \
            s16x8 af;                                                       \
            af[0]=f2b(f0.x); af[1]=f2b(f0.y); af[2]=f2b(f0.z); af[3]=f2b(f0.w); \
            af[4]=f2b(f1.x); af[5]=f2b(f1.y); af[6]=f2b(f1.z); af[7]=f2b(f1.w); \
            const int kb = ks * 64 + (kg << 4);                             \
            _Pragma("unroll")                                               \
            for (int ni = 0; ni < 8; ++ni) {                                \
                int rb = ni * 16 + colf;                                    \
                s16x8 bf = *(const s16x8*)(ldsB + (KT_) * 16384 + (rb << 7) \
                                           + (kb ^ ((rb & 7) << 4)));       \
                acc[ni] = __builtin_amdgcn_mfma_f32_16x16x32_bf16(          \
                    af, bf, acc[ni], 0, 0, 0);                              \
            }                                                               \
        }                                                                   \
    } while (0)

#define FENCE asm volatile("" ::: "memory")

    // per-lane A row base for rank r
    auto abase = [&](int r) -> const float* {
        int job = r >> 6, bb = r & 15;
        return x + ((size_t)(bb * TTOT + (int)JT0[job] + (wv << 4) + colf)) * DIN;
    };

    const float* pcur = abase(r0);
    ISSUE(0, pcur, 0); ISSUE(1, pcur, 1); ISSUE(2, pcur, 2);

    int key_cur = -1;
#pragma unroll 1
    for (int r = r0; r < rend; ++r) {
        const int job = r >> 6, nt = (r >> 4) & 3, bb = r & 15;
        const int t0 = JT0[job], g = JG[job], nw = JNW[job];
        const int key = (g << 2) | nt;
        if (key != key_cur) {
            key_cur = key;
            FENCE;
            __builtin_amdgcn_s_barrier();        // old-B readers done
            FENCE;
            const char* wsrc = (const char*)wbf + (size_t)key * 131072;
#pragma unroll
            for (int i = 0; i < 16; ++i) {
                __builtin_amdgcn_global_load_lds(
                    (const __attribute__((address_space(1))) void*)(wsrc + i * 8192 + tid * 16),
                    (__attribute__((address_space(3))) void*)(ldsB + i * 8192 + tid * 16),
                    16, 0, 0);
            }
            FENCE;
            asm volatile("s_waitcnt vmcnt(0)" ::: "memory");
            __builtin_amdgcn_s_barrier();        // B ready
            FENCE;
        }
        const bool hn = (r + 1 < rend);
        const float* pnext = hn ? abase(r + 1) : pcur;

        f32x4 acc[8];
#pragma unroll
        for (int ni = 0; ni < 8; ++ni) acc[ni] = (f32x4){0.f, 0.f, 0.f, 0.f};

        ISSUE(3, pcur, 3);            CONSUME(0, 0);
        ISSUE(0, pcur, 4);            CONSUME(1, 1);
        ISSUE(1, pcur, 5);            CONSUME(2, 2);
        ISSUE(2, pcur, 6);            CONSUME(3, 3);
        ISSUE(3, pcur, 7);            CONSUME(0, 4);
        if (hn) { ISSUE(0, pnext, 0); } CONSUME(1, 5);
        if (hn) { ISSUE(1, pnext, 1); } CONSUME(2, 6);
        if (hn) { ISSUE(2, pnext, 2); } CONSUME(3, 7);

        // ---- per-wave epilogue: transpose via private LDS slice, no barrier ----
        if (wv < nw) {
            const int n0 = nt << 7;
            const float4 b0 = *(const float4*)(bias + (g << 9) + n0 + (colf << 2));
            const float4 b1 = *(const float4*)(bias + (g << 9) + n0 + (colf << 2) + 64);
            const size_t orow0 = (size_t)bb * TTOT + t0 + (wv << 4);
#pragma unroll
            for (int j = 0; j < 4; ++j) {
#pragma unroll
                for (int ni = 0; ni < 8; ++ni)
                    cslice[kg * 132 + ni * 16 + colf] = acc[ni][j];
                float4 v0 = *(const float4*)(cslice + kg * 132 + (colf << 2));
                float4 v1 = *(const float4*)(cslice + kg * 132 + (colf << 2) + 64);
                float4 o0, o1;
                o0.x = v0.x + b0.x; o0.y = v0.y + b0.y;
                o0.z = v0.z + b0.z; o0.w = v0.w + b0.w;
                o1.x = v1.x + b1.x; o1.y = v1.y + b1.y;
                o1.z = v1.z + b1.z; o1.w = v1.w + b1.w;
                float* orow = out + (orow0 + (kg << 2) + j) * DOUT + n0;
                *(float4*)(orow + (colf << 2))      = o0;
                *(float4*)(orow + (colf << 2) + 64) = o1;
            }
        }
        pcur = pnext;
    }
#undef ISSUE
#undef CONSUME
#undef FENCE
}

// ---- Fallback (ws too small): R2-style 64x128 kernel, fp32 W path ----
__launch_bounds__(256)
__global__ void gemm_fallback(const float* __restrict__ x,
                              const float* __restrict__ W,
                              const float* __restrict__ bias,
                              float* __restrict__ out) {
    __shared__ __align__(16) char smem[49152];
    const int tid  = threadIdx.x;
    const int lane = tid & 63;
    const int wid  = tid >> 6;
    const int wm   = wid >> 1;
    const int wn   = wid & 1;
    const int p  = blockIdx.x;
    const int l  = ((p & 7) << 9) + (p >> 3);
    const int mt = l >> 2;
    const int nt = l & 3;
    const int bb = mt >> 6;
    const int t0 = (mt & 63) << 6;
    const int n0 = nt << 7;
    int g = 0;
    if (t0 >= 256)  g++; if (t0 >= 768)  g++; if (t0 >= 1536) g++;
    if (t0 >= 1920) g++; if (t0 >= 2560) g++; if (t0 >= 3072) g++;
    if (t0 >= 3648) g++;
    const int arow = tid >> 2;
    const int acol = (tid & 3) << 4;
    const float* aptr = x + ((size_t)(bb * TTOT + t0 + arow)) * DIN + acol;
    float4 a0, a1, a2, a3;
    float4 bw0[4], bw1[4];
    auto load_global = [&](int k0) {
        a0 = *(const float4*)(aptr + k0);
        a1 = *(const float4*)(aptr + k0 + 4);
        a2 = *(const float4*)(aptr + k0 + 8);
        a3 = *(const float4*)(aptr + k0 + 12);
#pragma unroll
        for (int pp = 0; pp < 4; ++pp) {
            int idx = pp * 256 + tid;
            int row = idx >> 3, seg = idx & 7;
            const float* wp = W + ((size_t)((g << 9) + n0 + row)) * DIN + k0 + (seg << 3);
            bw0[pp] = *(const float4*)(wp);
            bw1[pp] = *(const float4*)(wp + 4);
        }
    };
    auto swz = [](int row, int bc) { return (row << 7) + (bc ^ ((row & 7) << 4)); };
    auto write_lds = [&](int buf) {
        char* ab  = smem + buf * 8192;
        char* bb_ = smem + 16384 + buf * 16384;
        s16x8 w0, w1;
        w0[0]=f2b(a0.x); w0[1]=f2b(a0.y); w0[2]=f2b(a0.z); w0[3]=f2b(a0.w);
        w0[4]=f2b(a1.x); w0[5]=f2b(a1.y); w0[6]=f2b(a1.z); w0[7]=f2b(a1.w);
        w1[0]=f2b(a2.x); w1[1]=f2b(a2.y); w1[2]=f2b(a2.z); w1[3]=f2b(a2.w);
        w1[4]=f2b(a3.x); w1[5]=f2b(a3.y); w1[6]=f2b(a3.z); w1[7]=f2b(a3.w);
        const int abase2 = acol << 1;
        *(s16x8*)(ab + swz(arow, abase2))      = w0;
        *(s16x8*)(ab + swz(arow, abase2 + 16)) = w1;
#pragma unroll
        for (int pp = 0; pp < 4; ++pp) {
            int idx = pp * 256 + tid;
            int row = idx >> 3, seg = idx & 7;
            s16x8 wvv;
            wvv[0]=f2b(bw0[pp].x); wvv[1]=f2b(bw0[pp].y);
            wvv[2]=f2b(bw0[pp].z); wvv[3]=f2b(bw0[pp].w);
            wvv[4]=f2b(bw1[pp].x); wvv[5]=f2b(bw1[pp].y);
            wvv[6]=f2b(bw1[pp].z); wvv[7]=f2b(bw1[pp].w);
            *(s16x8*)(bb_ + swz(row, seg << 4)) = wvv;
        }
    };
    f32x4 acc[2][4];
#pragma unroll
    for (int mi = 0; mi < 2; ++mi)
#pragma unroll
        for (int ni = 0; ni < 4; ++ni) acc[mi][ni] = (f32x4){0.f,0.f,0.f,0.f};
    const int colf = lane & 15;
    const int kgrp = lane >> 4;
    auto compute = [&](int buf) {
        const char* ab  = smem + buf * 8192;
        const char* bb_ = smem + 16384 + buf * 16384;
#pragma unroll
        for (int ks = 0; ks < 2; ++ks) {
            const int kb = ks * 64 + kgrp * 16;
            s16x8 af[2], bf[4];
#pragma unroll
            for (int mi = 0; mi < 2; ++mi)
                af[mi] = *(const s16x8*)(ab + swz(wm * 32 + mi * 16 + colf, kb));
#pragma unroll
            for (int ni = 0; ni < 4; ++ni)
                bf[ni] = *(const s16x8*)(bb_ + swz(wn * 64 + ni * 16 + colf, kb));
#pragma unroll
            for (int mi = 0; mi < 2; ++mi)
#pragma unroll
                for (int ni = 0; ni < 4; ++ni)
                    acc[mi][ni] = __builtin_amdgcn_mfma_f32_16x16x32_bf16(
                        af[mi], bf[ni], acc[mi][ni], 0, 0, 0);
        }
    };
    load_global(0);
    write_lds(0);
    __syncthreads();
    int buf = 0;
#pragma unroll 1
    for (int kt = 0; kt < 8; ++kt) {
        if (kt < 7) load_global((kt + 1) << 6);
        compute(buf);
        if (kt < 7) write_lds(buf ^ 1);
        __syncthreads();
        buf ^= 1;
    }
    float* cbuf = (float*)smem;
#pragma unroll
    for (int ni = 0; ni < 4; ++ni) {
        const int c = wn * 64 + ni * 16 + colf;
#pragma unroll
        for (int mi = 0; mi < 2; ++mi) {
            const int r = wm * 32 + mi * 16 + kgrp * 4;
            f32x4 v = acc[mi][ni];
            cbuf[(r + 0) * 132 + c] = v[0];
            cbuf[(r + 1) * 132 + c] = v[1];
            cbuf[(r + 2) * 132 + c] = v[2];
            cbuf[(r + 3) * 132 + c] = v[3];
        }
    }
    __syncthreads();
    const int rr = tid >> 5;
    const int cc = (tid & 31) << 2;
    const float4 bv = *(const float4*)(bias + (g << 9) + n0 + cc);
#pragma unroll
    for (int it = 0; it < 8; ++it) {
        const int row = it * 8 + rr;
        float4 v = *(const float4*)(cbuf + row * 132 + cc);
        float4 o4; o4.x = v.x + bv.x; o4.y = v.y + bv.y;
                   o4.z = v.z + bv.z; o4.w = v.w + bv.w;
        *(float4*)(out + ((size_t)(bb * TTOT) + t0 + row) * DOUT + n0 + cc) = o4;
    }
}

extern "C" void kernel_launch(void* const* d_in, const int* in_sizes, int n_in,
                              void* d_out, int out_size, void* d_ws, size_t ws_size,
                              hipStream_t stream) {
    const float* x    = (const float*)d_in[0];
    const float* W    = (const float*)d_in[1];
    const float* bias = (const float*)d_in[2];
    float* out = (float*)d_out;

    const size_t wbytes = (size_t)NG * DOUT * DIN * sizeof(ushort);  // 4 MB

    if (ws_size >= wbytes) {
        ushort* wbf = (ushort*)d_ws;
        wconv_kernel<<<1024, 256, 0, stream>>>(W, wbf);
        gemm_kernel<<<256, 512, 0, stream>>>(x, wbf, bias, out);
    } else {
        gemm_fallback<<<BATCH * 64 * 4, 256, 0, stream>>>(x, W, bias, out);
    }
}

// Round 5
// 95.615 us; speedup vs baseline: 1.1050x; 1.1050x over previous
//
#include <hip/hip_runtime.h>
#include <hip/hip_bf16.h>
#include <cstdint>

#define BATCH 16
#define TTOT  4096
#define DIN   512
#define DOUT  512
#define NG    8
#define NJOB  33
#define NKT   8

typedef float f32x4 __attribute__((ext_vector_type(4)));
typedef short s16x8 __attribute__((ext_vector_type(8)));

__device__ __forceinline__ short f2b(float f) {
    union { __bf16 b; short s; } u; u.b = (__bf16)f; return u.s;
}

// M-tile jobs per batch (BM=128): 31 full tiles + two 64-row stubs (3584/3648).
__device__ __constant__ short JT0[NJOB] = {
    0,128, 256,384,512,640, 768,896,1024,1152,1280,1408, 1536,1664,1792,
    1920,2048,2176,2304,2432, 2560,2688,2816,2944, 3072,3200,3328,3456,
    3584, 3648, 3712,3840,3968};
__device__ __constant__ char JG[NJOB] = {
    0,0, 1,1,1,1, 2,2,2,2,2,2, 3,3,3, 4,4,4,4,4, 5,5,5,5, 6,6,6,6, 6, 7, 7,7,7};
__device__ __constant__ char JBM[NJOB] = {
    127,127, 127,127,127,127, 127,127,127,127,127,127, 127,127,127,
    127,127,127,127,127, 127,127,127,127, 127,127,127,127, 63, 63, 127,127,127};

// ---- Kernel 1: W fp32 -> bf16, pre-swizzled LDS-image chunks ----
// chunk c = (g*4+nt)*8+kt (16KB): chunk[row*128+bc] = bf16 W[g][nt*128+row]
//   [kt*64 + ((bc ^ ((row&7)<<4))>>1)]
__global__ void wconv_kernel(const float* __restrict__ W, ushort* __restrict__ wbf) {
    int gid = blockIdx.x * 256 + threadIdx.x;
    int c = gid >> 10;
    int q = (gid & 1023) << 4;
    int row = q >> 7;
    int bc  = q & 127;
    int kbyte = bc ^ ((row & 7) << 4);
    int kt = c & 7, nt = (c >> 3) & 3, g = c >> 5;
    const float* wp = W + ((size_t)(g * DOUT + nt * 128 + row)) * DIN
                        + kt * 64 + (kbyte >> 1);
    float4 v0 = *reinterpret_cast<const float4*>(wp);
    float4 v1 = *reinterpret_cast<const float4*>(wp + 4);
    s16x8 o;
    o[0]=f2b(v0.x); o[1]=f2b(v0.y); o[2]=f2b(v0.z); o[3]=f2b(v0.w);
    o[4]=f2b(v1.x); o[5]=f2b(v1.y); o[6]=f2b(v1.z); o[7]=f2b(v1.w);
    *reinterpret_cast<s16x8*>((char*)wbf + (size_t)c * 16384 + q) = o;
}

// ---- Kernel 2: grouped GEMM 128x128x64, 4 waves, wave-tile 64x64,
//      A reg-staged 2-deep + cvt, B gload_lds ring-3, counted vmcnt ----
__launch_bounds__(256, 2)
__global__ void gemm_kernel(const float* __restrict__ x,
                            const ushort* __restrict__ wbf,
                            const float* __restrict__ bias,
                            float* __restrict__ out) {
    __shared__ __align__(16) char smem[81920];  // A dbuf 32K | B ring 48K; C overlay

    const int tid  = threadIdx.x;
    const int lane = tid & 63;
    const int wv   = tid >> 6;      // 0..3
    const int wm   = wv >> 1;       // 0..1 : 64-row slab
    const int wn   = wv & 1;        // 0..1 : 64-col slab
    const int colf = lane & 15;
    const int kg   = lane >> 4;

    const int p    = blockIdx.x;
    const int l    = (p & 7) * 264 + (p >> 3);   // XCD-chunked, 2112 = 8*264
    const int nt   = l & 3;                       // n-tile fastest (x L2 reuse)
    const int rest = l >> 2;                      // 0..527
    const int job  = rest >> 4;                   // 0..32
    const int bb   = rest & 15;
    const int t0   = JT0[job];
    const int g    = JG[job];
    const int bmm1 = JBM[job];
    const int n0   = nt << 7;

    const char* bchunk = (const char*)wbf + (size_t)((g * 4 + nt) * 8) * 16384;

    char* abufs = smem;            // 2 x 16384
    char* bring = smem + 32768;    // 3 x 16384

    // A staging: wave wv stages rows wv*32..+31. Per j (0..3): row =
    // wv*32 + (lane>>3) + j*8, two float4 at fp32 cols (lane&7)*8 and +4.
    const int arow_s = (wv << 5) + (lane >> 3);
    const int col8   = (lane & 7) << 3;
    const float* aptr = x + ((size_t)(bb * TTOT + t0 + arow_s)) * DIN + col8;

    float4 stE[4][2], stO[4][2];

#define ISSUE_A(S, KT_) do {                                                \
        _Pragma("unroll")                                                   \
        for (int j_ = 0; j_ < 4; ++j_) {                                    \
            const float* p_ = aptr + (size_t)(j_ * 8) * DIN + ((KT_) << 6); \
            st##S[j_][0] = *(const float4*)(p_);                            \
            st##S[j_][1] = *(const float4*)(p_ + 4);                        \
        }                                                                   \
    } while (0)

#define ISSUE_B(KT_) do {                                                   \
        const char* src_ = bchunk + (size_t)(KT_) * 16384 + tid * 16;       \
        char* dst_ = bring + ((KT_) % 3) * 16384 + tid * 16;                \
        _Pragma("unroll")                                                   \
        for (int i_ = 0; i_ < 4; ++i_) {                                    \
            __builtin_amdgcn_global_load_lds(                               \
                (const __attribute__((address_space(1))) void*)(src_ + i_ * 4096), \
                (__attribute__((address_space(3))) void*)(dst_ + i_ * 4096),\
                16, 0, 0);                                                  \
        }                                                                   \
    } while (0)

#define CVT_WRITE_A(S, KT_) do {                                            \
        char* ab_ = abufs + ((KT_) & 1) * 16384;                            \
        _Pragma("unroll")                                                   \
        for (int j_ = 0; j_ < 4; ++j_) {                                    \
            float4 lo_ = st##S[j_][0], hi_ = st##S[j_][1];                  \
            s16x8 o_;                                                       \
            o_[0]=f2b(lo_.x); o_[1]=f2b(lo_.y); o_[2]=f2b(lo_.z); o_[3]=f2b(lo_.w); \
            o_[4]=f2b(hi_.x); o_[5]=f2b(hi_.y); o_[6]=f2b(hi_.z); o_[7]=f2b(hi_.w); \
            int row_ = arow_s + j_ * 8;                                     \
            int bc_ = (col8 << 1) ^ ((row_ & 7) << 4);                      \
            *(s16x8*)(ab_ + (row_ << 7) + bc_) = o_;                        \
        }                                                                   \
    } while (0)

#define COMPUTE(KT_) do {                                                   \
        const char* ab_ = abufs + ((KT_) & 1) * 16384;                      \
        const char* bb_ = bring + ((KT_) % 3) * 16384;                      \
        _Pragma("unroll")                                                   \
        for (int ks = 0; ks < 2; ++ks) {                                    \
            const int kb = ks * 64 + (kg << 4);                             \
            s16x8 af[4], bf[4];                                             \
            _Pragma("unroll")                                               \
            for (int mi = 0; mi < 4; ++mi) {                                \
                int r_ = wm * 64 + mi * 16 + colf;                          \
                af[mi] = *(const s16x8*)(ab_ + (r_ << 7) + (kb ^ ((r_ & 7) << 4))); \
            }                                                               \
            _Pragma("unroll")                                               \
            for (int ni = 0; ni < 4; ++ni) {                                \
                int r_ = wn * 64 + ni * 16 + colf;                          \
                bf[ni] = *(const s16x8*)(bb_ + (r_ << 7) + (kb ^ ((r_ & 7) << 4))); \
            }                                                               \
            _Pragma("unroll")                                               \
            for (int mi = 0; mi < 4; ++mi)                                  \
                _Pragma("unroll")                                           \
                for (int ni = 0; ni < 4; ++ni)                              \
                    acc[mi][ni] = __builtin_amdgcn_mfma_f32_16x16x32_bf16(  \
                        af[mi], bf[ni], acc[mi][ni], 0, 0, 0);              \
        }                                                                   \
    } while (0)

#define FENCE   asm volatile("" ::: "memory")
#define WAITV12 asm volatile("s_waitcnt vmcnt(12)" ::: "memory")
#define WAITV0  asm volatile("s_waitcnt vmcnt(0)" ::: "memory")
#define WAITL0  asm volatile("s_waitcnt lgkmcnt(0)" ::: "memory")
#define BARRIER do { FENCE; __builtin_amdgcn_s_barrier(); FENCE; } while (0)

    f32x4 acc[4][4];
#pragma unroll
    for (int mi = 0; mi < 4; ++mi)
#pragma unroll
        for (int ni = 0; ni < 4; ++ni)
            acc[mi][ni] = (f32x4){0.f, 0.f, 0.f, 0.f};

    // ---- prologue: tiles 0,1 in flight ----
    ISSUE_A(E, 0); ISSUE_B(0);
    FENCE;
    ISSUE_A(O, 1); ISSUE_B(1);
    FENCE;
    CVT_WRITE_A(E, 0);
    WAITV12;     // B(0) landed; A(1)+B(1)=12 ride on
    WAITL0;
    BARRIER;

#pragma unroll
    for (int kt = 0; kt < NKT; ++kt) {
        if (kt + 2 < NKT) {
            if (((kt) & 1) == 0) { ISSUE_A(E, kt + 2); } else { ISSUE_A(O, kt + 2); }
            ISSUE_B(kt + 2);
            FENCE;
        }
        COMPUTE(kt);
        if (kt + 1 < NKT) {
            if (((kt + 1) & 1) == 0) { CVT_WRITE_A(E, kt + 1); }
            else                     { CVT_WRITE_A(O, kt + 1); }
            if (kt + 2 < NKT) { WAITV12; }   // B(kt+1) done; tile kt+2 in flight
            else              { WAITV0;  }   // tail drain
            WAITL0;
            BARRIER;
        }
    }
    BARRIER;   // all LDS reads done before C overlay

    // ---- epilogue: stage C (128 x 132 f32) in LDS, write coalesced ----
    float* cbuf = (float*)smem;
#pragma unroll
    for (int mi = 0; mi < 4; ++mi)
#pragma unroll
        for (int ni = 0; ni < 4; ++ni) {
            int r0 = wm * 64 + mi * 16 + kg * 4;
            int c  = wn * 64 + ni * 16 + colf;
            f32x4 v = acc[mi][ni];
            cbuf[(r0 + 0) * 132 + c] = v[0];
            cbuf[(r0 + 1) * 132 + c] = v[1];
            cbuf[(r0 + 2) * 132 + c] = v[2];
            cbuf[(r0 + 3) * 132 + c] = v[3];
        }
    WAITL0;
    BARRIER;

    const int rr = tid >> 5;            // 0..7
    const int cc = (tid & 31) << 2;     // 0..124
    float4 bv = *reinterpret_cast<const float4*>(bias + (g << 9) + n0 + cc);
#pragma unroll
    for (int it = 0; it < 16; ++it) {
        int row = it * 8 + rr;
        if (row <= bmm1) {
            float4 v = *reinterpret_cast<const float4*>(cbuf + row * 132 + cc);
            float4 o4; o4.x = v.x + bv.x; o4.y = v.y + bv.y;
                       o4.z = v.z + bv.z; o4.w = v.w + bv.w;
            *reinterpret_cast<float4*>(
                out + ((size_t)(bb * TTOT + t0 + row)) * DOUT + n0 + cc) = o4;
        }
    }
#undef ISSUE_A
#undef ISSUE_B
#undef CVT_WRITE_A
#undef COMPUTE
#undef FENCE
#undef WAITV12
#undef WAITV0
#undef WAITL0
#undef BARRIER
}

// ---- Fallback (ws too small): R2-style 64x128 kernel, fp32 W path ----
__launch_bounds__(256)
__global__ void gemm_fallback(const float* __restrict__ x,
                              const float* __restrict__ W,
                              const float* __restrict__ bias,
                              float* __restrict__ out) {
    __shared__ __align__(16) char smem[49152];
    const int tid  = threadIdx.x;
    const int lane = tid & 63;
    const int wid  = tid >> 6;
    const int wm   = wid >> 1;
    const int wn   = wid & 1;
    const int p  = blockIdx.x;
    const int l  = ((p & 7) << 9) + (p >> 3);
    const int mt = l >> 2;
    const int nt = l & 3;
    const int bb = mt >> 6;
    const int t0 = (mt & 63) << 6;
    const int n0 = nt << 7;
    int g = 0;
    if (t0 >= 256)  g++; if (t0 >= 768)  g++; if (t0 >= 1536) g++;
    if (t0 >= 1920) g++; if (t0 >= 2560) g++; if (t0 >= 3072) g++;
    if (t0 >= 3648) g++;
    const int arow = tid >> 2;
    const int acol = (tid & 3) << 4;
    const float* aptr = x + ((size_t)(bb * TTOT + t0 + arow)) * DIN + acol;
    float4 a0, a1, a2, a3;
    float4 bw0[4], bw1[4];
    auto load_global = [&](int k0) {
        a0 = *(const float4*)(aptr + k0);
        a1 = *(const float4*)(aptr + k0 + 4);
        a2 = *(const float4*)(aptr + k0 + 8);
        a3 = *(const float4*)(aptr + k0 + 12);
#pragma unroll
        for (int pp = 0; pp < 4; ++pp) {
            int idx = pp * 256 + tid;
            int row = idx >> 3, seg = idx & 7;
            const float* wp = W + ((size_t)((g << 9) + n0 + row)) * DIN + k0 + (seg << 3);
            bw0[pp] = *(const float4*)(wp);
            bw1[pp] = *(const float4*)(wp + 4);
        }
    };
    auto swz = [](int row, int bc) { return (row << 7) + (bc ^ ((row & 7) << 4)); };
    auto write_lds = [&](int buf) {
        char* ab  = smem + buf * 8192;
        char* bb_ = smem + 16384 + buf * 16384;
        s16x8 w0, w1;
        w0[0]=f2b(a0.x); w0[1]=f2b(a0.y); w0[2]=f2b(a0.z); w0[3]=f2b(a0.w);
        w0[4]=f2b(a1.x); w0[5]=f2b(a1.y); w0[6]=f2b(a1.z); w0[7]=f2b(a1.w);
        w1[0]=f2b(a2.x); w1[1]=f2b(a2.y); w1[2]=f2b(a2.z); w1[3]=f2b(a2.w);
        w1[4]=f2b(a3.x); w1[5]=f2b(a3.y); w1[6]=f2b(a3.z); w1[7]=f2b(a3.w);
        const int abase2 = acol << 1;
        *(s16x8*)(ab + swz(arow, abase2))      = w0;
        *(s16x8*)(ab + swz(arow, abase2 + 16)) = w1;
#pragma unroll
        for (int pp = 0; pp < 4; ++pp) {
            int idx = pp * 256 + tid;
            int row = idx >> 3, seg = idx & 7;
            s16x8 wvv;
            wvv[0]=f2b(bw0[pp].x); wvv[1]=f2b(bw0[pp].y);
            wvv[2]=f2b(bw0[pp].z); wvv[3]=f2b(bw0[pp].w);
            wvv[4]=f2b(bw1[pp].x); wvv[5]=f2b(bw1[pp].y);
            wvv[6]=f2b(bw1[pp].z); wvv[7]=f2b(bw1[pp].w);
            *(s16x8*)(bb_ + swz(row, seg << 4)) = wvv;
        }
    };
    f32x4 acc[2][4];
#pragma unroll
    for (int mi = 0; mi < 2; ++mi)
#pragma unroll
        for (int ni = 0; ni < 4; ++ni) acc[mi][ni] = (f32x4){0.f,0.f,0.f,0.f};
    const int colf = lane & 15;
    const int kgrp = lane >> 4;
    auto compute = [&](int buf) {
        const char* ab  = smem + buf * 8192;
        const char* bb_ = smem + 16384 + buf * 16384;
#pragma unroll
        for (int ks = 0; ks < 2; ++ks) {
            const int kb = ks * 64 + kgrp * 16;
            s16x8 af[2], bf[4];
#pragma unroll
            for (int mi = 0; mi < 2; ++mi)
                af[mi] = *(const s16x8*)(ab + swz(wm * 32 + mi * 16 + colf, kb));
#pragma unroll
            for (int ni = 0; ni < 4; ++ni)
                bf[ni] = *(const s16x8*)(bb_ + swz(wn * 64 + ni * 16 + colf, kb));
#pragma unroll
            for (int mi = 0; mi < 2; ++mi)
#pragma unroll
                for (int ni = 0; ni < 4; ++ni)
                    acc[mi][ni] = __builtin_amdgcn_mfma_f32_16x16x32_bf16(
                        af[mi], bf[ni], acc[mi][ni], 0, 0, 0);
        }
    };
    load_global(0);
    write_lds(0);
    __syncthreads();
    int buf = 0;
#pragma unroll 1
    for (int kt = 0; kt < 8; ++kt) {
        if (kt < 7) load_global((kt + 1) << 6);
        compute(buf);
        if (kt < 7) write_lds(buf ^ 1);
        __syncthreads();
        buf ^= 1;
    }
    float* cbuf = (float*)smem;
#pragma unroll
    for (int ni = 0; ni < 4; ++ni) {
        const int c = wn * 64 + ni * 16 + colf;
#pragma unroll
        for (int mi = 0; mi < 2; ++mi) {
            const int r = wm * 32 + mi * 16 + kgrp * 4;
            f32x4 v = acc[mi][ni];
            cbuf[(r + 0) * 132 + c] = v[0];
            cbuf[(r + 1) * 132 + c] = v[1];
            cbuf[(r + 2) * 132 + c] = v[2];
            cbuf[(r + 3) * 132 + c] = v[3];
        }
    }
    __syncthreads();
    const int rr = tid >> 5;
    const int cc = (tid & 31) << 2;
    const float4 bv = *(const float4*)(bias + (g << 9) + n0 + cc);
#pragma unroll
    for (int it = 0; it < 8; ++it) {
        const int row = it * 8 + rr;
        float4 v = *(const float4*)(cbuf + row * 132 + cc);
        float4 o4; o4.x = v.x + bv.x; o4.y = v.y + bv.y;
                   o4.z = v.z + bv.z; o4.w = v.w + bv.w;
        *(float4*)(out + ((size_t)(bb * TTOT) + t0 + row) * DOUT + n0 + cc) = o4;
    }
}

extern "C" void kernel_launch(void* const* d_in, const int* in_sizes, int n_in,
                              void* d_out, int out_size, void* d_ws, size_t ws_size,
                              hipStream_t stream) {
    const float* x    = (const float*)d_in[0];
    const float* W    = (const float*)d_in[1];
    const float* bias = (const float*)d_in[2];
    float* out = (float*)d_out;

    const size_t wbytes = (size_t)NG * DOUT * DIN * sizeof(ushort);  // 4 MB

    if (ws_size >= wbytes) {
        ushort* wbf = (ushort*)d_ws;
        wconv_kernel<<<1024, 256, 0, stream>>>(W, wbf);
        gemm_kernel<<<NJOB * BATCH * 4, 256, 0, stream>>>(x, wbf, bias, out);
    } else {
        gemm_fallback<<<BATCH * 64 * 4, 256, 0, stream>>>(x, W, bias, out);
    }
}